// Round 3
// baseline (758.541 us; speedup 1.0000x reference)
//
#include <hip/hip_runtime.h>
#include <math.h>

#define N 8192
#define IN_DIM 128
#define HID 32

#define RBW 128          // rows per wave in spmm
#define RB 512           // rows per block (4 waves)
#define SK 64            // split-K factor
#define KCHUNK (N / SK)  // 128

__device__ __forceinline__ void fma4(float4& acc, float a, const float4& b) {
    acc.x = fmaf(a, b.x, acc.x);
    acc.y = fmaf(a, b.y, acc.y);
    acc.z = fmaf(a, b.z, acc.z);
    acc.w = fmaf(a, b.w, acc.w);
}

// degree[i] = 1 + sum_j adj[i][j];  dinv[i] = 1/sqrt(max(degree,1))
__global__ __launch_bounds__(256) void k_degree(const float* __restrict__ adj,
                                                float* __restrict__ dinv) {
    int row = blockIdx.x;
    const float4* rp = (const float4*)(adj + (size_t)row * N);
    int t = threadIdx.x;
    float s = 0.f;
#pragma unroll
    for (int i = 0; i < 8; ++i) {
        float4 v = rp[t + i * 256];
        s += v.x + v.y + v.z + v.w;
    }
    for (int off = 32; off > 0; off >>= 1) s += __shfl_down(s, off, 64);
    __shared__ float red[4];
    if ((t & 63) == 0) red[t >> 6] = s;
    __syncthreads();
    if (t == 0) {
        float deg = red[0] + red[1] + red[2] + red[3] + 1.0f;  // +1 self loop
        deg = fmaxf(deg, 1.0f);
        dinv[row] = 1.0f / sqrtf(deg);
    }
}

// Zs[i][c] = dinv[i] * (x[i] @ W1 + b1)[c]   (x: [N,128], W1: [128,32])
__global__ __launch_bounds__(256) void k_z1(const float* __restrict__ x,
                                            const float* __restrict__ W1,
                                            const float* __restrict__ b1,
                                            const float* __restrict__ dinv,
                                            float* __restrict__ Zs) {
    __shared__ float Ws[IN_DIM * HID];  // 4096 floats
    __shared__ float xs[8 * IN_DIM];    // 1024 floats
    int t = threadIdx.x;
    int row0 = blockIdx.x * 8;
#pragma unroll
    for (int i = 0; i < 4; ++i)
        *(float4*)&Ws[(i * 256 + t) * 4] = *(const float4*)&W1[(i * 256 + t) * 4];
    *(float4*)&xs[t * 4] = *(const float4*)&x[(size_t)row0 * IN_DIM + t * 4];
    __syncthreads();
    int r = t >> 5, c = t & 31;
    float acc = b1[c];
#pragma unroll 8
    for (int k = 0; k < IN_DIM; ++k) acc = fmaf(xs[r * IN_DIM + k], Ws[k * HID + c], acc);
    int row = row0 + r;
    Zs[(size_t)row * HID + c] = dinv[row] * acc;
}

// P[sk] = adj[rows, kchunk_sk] @ Zs[kchunk_sk, 32]
// No LDS, no barriers. Each thread owns 2 rows x ALL 32 cols:
//  - A streams global->VGPR (each 64B adj line consumed by the same thread
//    over 4 consecutive k-steps -> L1/L2 line reuse, HBM traffic = 1x).
//  - B (Zs row, 32 floats) is wave-uniform -> scalar/broadcast loads from a
//    16 KB L1-resident chunk.
// Mem-inst : FMA-inst ratio = 34 : 256 per 4-k step (vs 10 : 64 via LDS).
__global__ __launch_bounds__(256, 4) void k_spmm(const float* __restrict__ adj,
                                                 const float* __restrict__ Zs,
                                                 float* __restrict__ P) {
    int t = threadIdx.x;
    int w = t >> 6, l = t & 63;
    int row = blockIdx.x * RB + w * RBW + l * 2;  // this thread: rows row, row+1
    int kbeg = blockIdx.y * KCHUNK;
    const float* a0 = adj + (size_t)row * N;
    const float* a1 = a0 + N;
    float4 acc0[8] = {{0,0,0,0},{0,0,0,0},{0,0,0,0},{0,0,0,0},
                      {0,0,0,0},{0,0,0,0},{0,0,0,0},{0,0,0,0}};
    float4 acc1[8] = {{0,0,0,0},{0,0,0,0},{0,0,0,0},{0,0,0,0},
                      {0,0,0,0},{0,0,0,0},{0,0,0,0},{0,0,0,0}};

#pragma unroll 2
    for (int k = kbeg; k < kbeg + KCHUNK; k += 4) {
        float4 A0 = *(const float4*)&a0[k];
        float4 A1 = *(const float4*)&a1[k];
        const float* B = Zs + (size_t)k * HID;  // wave-uniform address
        float a0j[4] = {A0.x, A0.y, A0.z, A0.w};
        float a1j[4] = {A1.x, A1.y, A1.z, A1.w};
#pragma unroll
        for (int j = 0; j < 4; ++j) {
#pragma unroll
            for (int cc = 0; cc < 8; ++cc) {
                float4 b = *(const float4*)&B[j * HID + cc * 4];
                fma4(acc0[cc], a0j[j], b);
                fma4(acc1[cc], a1j[j], b);
            }
        }
    }

    float* p0 = P + (size_t)blockIdx.y * (N * HID) + (size_t)row * HID;
#pragma unroll
    for (int cc = 0; cc < 8; ++cc) *(float4*)&p0[cc * 4] = acc0[cc];
#pragma unroll
    for (int cc = 0; cc < 8; ++cc) *(float4*)&p0[HID + cc * 4] = acc1[cc];
}

// H = relu(dinv * (sum_sk P[sk] + Zs)); then Zout = dinv * (H @ W2 + b2)   (fused fin+z2)
__global__ __launch_bounds__(256) void k_fin_z2(const float* __restrict__ P,
                                                const float* __restrict__ Zin,
                                                const float* __restrict__ dinv,
                                                const float* __restrict__ W2,
                                                const float* __restrict__ b2,
                                                float* __restrict__ Zout) {
    __shared__ float Ws[HID * HID];  // 1024 floats
    __shared__ float hs[8][HID];
    int t = threadIdx.x;
    int row0 = blockIdx.x * 8;
    *(float4*)&Ws[t * 4] = *(const float4*)&W2[t * 4];
    int r = t >> 5, c = t & 31;
    size_t idx = (size_t)row0 * HID + t;   // 256 consecutive elements
    float v = Zin[idx];
#pragma unroll
    for (int s = 0; s < SK; ++s) v += P[(size_t)s * (N * HID) + idx];
    int row = row0 + r;
    hs[r][c] = fmaxf(dinv[row] * v, 0.f);
    __syncthreads();
    float acc = b2[c];
#pragma unroll
    for (int k = 0; k < HID; ++k) acc = fmaf(hs[r][k], Ws[k * HID + c], acc);
    Zout[idx] = dinv[row] * acc;
}

// H = relu(dinv * (sum_sk P[sk] + Zs)); out[i] = H[i] @ W3 + b3   (fused fin+out)
__global__ __launch_bounds__(256) void k_fin_out(const float* __restrict__ P,
                                                 const float* __restrict__ Zin,
                                                 const float* __restrict__ dinv,
                                                 const float* __restrict__ W3,
                                                 const float* __restrict__ b3,
                                                 float* __restrict__ out) {
    int t = threadIdx.x;
    size_t idx = (size_t)blockIdx.x * 256 + t;
    int row = (int)(idx >> 5);
    int c = t & 31;
    float v = Zin[idx];
#pragma unroll
    for (int s = 0; s < SK; ++s) v += P[(size_t)s * (N * HID) + idx];
    float h = fmaxf(dinv[row] * v, 0.f);
    float hw = h * W3[c];
#pragma unroll
    for (int off = 16; off > 0; off >>= 1) hw += __shfl_xor(hw, off, 32);
    if (c == 0) out[row] = hw + b3[0];
}

extern "C" void kernel_launch(void* const* d_in, const int* in_sizes, int n_in,
                              void* d_out, int out_size, void* d_ws, size_t ws_size,
                              hipStream_t stream) {
    const float* x   = (const float*)d_in[0];
    const float* adj = (const float*)d_in[1];
    const float* W1  = (const float*)d_in[2];
    const float* b1  = (const float*)d_in[3];
    const float* W2  = (const float*)d_in[4];
    const float* b2  = (const float*)d_in[5];
    const float* W3  = (const float*)d_in[6];
    const float* b3  = (const float*)d_in[7];
    float* out = (float*)d_out;

    float* dinv = (float*)d_ws;               // N floats
    float* Zs1  = dinv + N;                   // N*32 floats (1 MB)
    float* Zs2  = Zs1 + (size_t)N * HID;      // N*32 floats (1 MB)
    float* P    = Zs2 + (size_t)N * HID;      // SK*N*32 floats (64 MB)

    k_degree<<<N, 256, 0, stream>>>(adj, dinv);
    k_z1<<<N / 8, 256, 0, stream>>>(x, W1, b1, dinv, Zs1);

    k_spmm<<<dim3(N / RB, SK), 256, 0, stream>>>(adj, Zs1, P);
    k_fin_z2<<<N / 8, 256, 0, stream>>>(P, Zs1, dinv, W2, b2, Zs2);

    k_spmm<<<dim3(N / RB, SK), 256, 0, stream>>>(adj, Zs2, P);
    k_fin_out<<<N * HID / 256, 256, 0, stream>>>(P, Zs2, dinv, W3, b3, out);
}

// Round 4
// 643.532 us; speedup vs baseline: 1.1787x; 1.1787x over previous
//
#include <hip/hip_runtime.h>
#include <math.h>

#define N 8192
#define IN_DIM 128
#define HID 32

#define RB 256           // rows per spmm block (one per thread)
#define KT 32            // k-tile staged in LDS
#define SK 32            // split-K factor (grid 32x32 = 1024 blocks)
#define KCHUNK (N / SK)  // 256

// degree[i] = 1 + sum_j adj[i][j];  dinv[i] = 1/sqrt(max(degree,1))
__global__ __launch_bounds__(256) void k_degree(const float* __restrict__ adj,
                                                float* __restrict__ dinv) {
    int row = blockIdx.x;
    const float4* rp = (const float4*)(adj + (size_t)row * N);
    int t = threadIdx.x;
    float s = 0.f;
#pragma unroll
    for (int i = 0; i < 8; ++i) {
        float4 v = rp[t + i * 256];
        s += v.x + v.y + v.z + v.w;
    }
    for (int off = 32; off > 0; off >>= 1) s += __shfl_down(s, off, 64);
    __shared__ float red[4];
    if ((t & 63) == 0) red[t >> 6] = s;
    __syncthreads();
    if (t == 0) {
        float deg = red[0] + red[1] + red[2] + red[3] + 1.0f;  // +1 self loop
        deg = fmaxf(deg, 1.0f);
        dinv[row] = 1.0f / sqrtf(deg);
    }
}

// Zs[i][c] = dinv[i] * (x[i] @ W1 + b1)[c]   (x: [N,128], W1: [128,32])
__global__ __launch_bounds__(256) void k_z1(const float* __restrict__ x,
                                            const float* __restrict__ W1,
                                            const float* __restrict__ b1,
                                            const float* __restrict__ dinv,
                                            float* __restrict__ Zs) {
    __shared__ float Ws[IN_DIM * HID];  // 4096 floats
    __shared__ float xs[8 * IN_DIM];    // 1024 floats
    int t = threadIdx.x;
    int row0 = blockIdx.x * 8;
#pragma unroll
    for (int i = 0; i < 4; ++i)
        *(float4*)&Ws[(i * 256 + t) * 4] = *(const float4*)&W1[(i * 256 + t) * 4];
    *(float4*)&xs[t * 4] = *(const float4*)&x[(size_t)row0 * IN_DIM + t * 4];
    __syncthreads();
    int r = t >> 5, c = t & 31;
    float acc = b1[c];
#pragma unroll 8
    for (int k = 0; k < IN_DIM; ++k) acc = fmaf(xs[r * IN_DIM + k], Ws[k * HID + c], acc);
    int row = row0 + r;
    Zs[(size_t)row * HID + c] = dinv[row] * acc;
}

// P[sk] = adj[rows, kchunk_sk] @ Zs[kchunk_sk, 32]
// Thread t owns row (r0+t), ALL 32 cols in registers.
//  - A staged in LDS, float-granular XOR swizzle (row,k) -> row*32 + (k ^ (row&31)):
//    * staging writes: bank = (4(t&7)+m) ^ (t>>3) -> exactly 2 lanes/bank (free, m136)
//    * compute reads:  bank = kk ^ (t&31)        -> 2 addrs/bank over wave (free)
//  - B row Zs[k][0..31] is wave-uniform -> scalar loads, zero per-lane VMEM.
// Per thread per tile: 1024 FMA vs 32 ds_read_b32 + 32 ds_write_b32 + 8 global float4.
__global__ __launch_bounds__(256, 4) void k_spmm(const float* __restrict__ adj,
                                                 const float* __restrict__ Zs,
                                                 float* __restrict__ P) {
    __shared__ float As[RB * KT];  // 32 KB, swizzled
    int t = threadIdx.x;
    int r0 = blockIdx.x * RB;
    int k0 = blockIdx.y * KCHUNK;
    int rkey = t & 31;
    float acc[HID];
#pragma unroll
    for (int c = 0; c < HID; ++c) acc[c] = 0.f;

    for (int tile = 0; tile < KCHUNK; tile += KT) {
        int kt = k0 + tile;
        // stage A tile: 256 rows x 32 k. 8 float4 global loads, swizzled b32 LDS writes.
#pragma unroll
        for (int i = 0; i < 8; ++i) {
            int g = i * 256 + t;
            int srow = g >> 3;           // 0..255
            int fj = (g & 7) * 4;        // 0,4,...,28
            float4 v = *(const float4*)&adj[(size_t)(r0 + srow) * N + kt + fj];
            int base = srow * KT;
            int key = srow & 31;
            As[base + ((fj + 0) ^ key)] = v.x;
            As[base + ((fj + 1) ^ key)] = v.y;
            As[base + ((fj + 2) ^ key)] = v.z;
            As[base + ((fj + 3) ^ key)] = v.w;
        }
        __syncthreads();
        const float* B = Zs + (size_t)kt * HID;  // wave-uniform
#pragma unroll
        for (int kk = 0; kk < KT; ++kk) {
            float a = As[t * KT + (kk ^ rkey)];
            const float* Bk = B + kk * HID;      // wave-uniform
#pragma unroll
            for (int c = 0; c < HID; ++c) acc[c] = fmaf(a, Bk[c], acc[c]);
        }
        __syncthreads();  // protect LDS before next tile's writes
    }

    float* p = P + (size_t)blockIdx.y * (N * HID) + (size_t)(r0 + t) * HID;
#pragma unroll
    for (int c = 0; c < 8; ++c) *(float4*)&p[c * 4] = *(float4*)&acc[c * 4];
}

// H = relu(dinv * (sum_sk P[sk] + Zs)); then Zout = dinv * (H @ W2 + b2)   (fused fin+z2)
__global__ __launch_bounds__(256) void k_fin_z2(const float* __restrict__ P,
                                                const float* __restrict__ Zin,
                                                const float* __restrict__ dinv,
                                                const float* __restrict__ W2,
                                                const float* __restrict__ b2,
                                                float* __restrict__ Zout) {
    __shared__ float Ws[HID * HID];  // 1024 floats
    __shared__ float hs[8][HID];
    int t = threadIdx.x;
    int row0 = blockIdx.x * 8;
    *(float4*)&Ws[t * 4] = *(const float4*)&W2[t * 4];
    int r = t >> 5, c = t & 31;
    size_t idx = (size_t)row0 * HID + t;   // 256 consecutive elements
    float v = Zin[idx];
#pragma unroll
    for (int s = 0; s < SK; ++s) v += P[(size_t)s * (N * HID) + idx];
    int row = row0 + r;
    hs[r][c] = fmaxf(dinv[row] * v, 0.f);
    __syncthreads();
    float acc = b2[c];
#pragma unroll
    for (int k = 0; k < HID; ++k) acc = fmaf(hs[r][k], Ws[k * HID + c], acc);
    Zout[idx] = dinv[row] * acc;
}

// H = relu(dinv * (sum_sk P[sk] + Zs)); out[i] = H[i] @ W3 + b3   (fused fin+out)
__global__ __launch_bounds__(256) void k_fin_out(const float* __restrict__ P,
                                                 const float* __restrict__ Zin,
                                                 const float* __restrict__ dinv,
                                                 const float* __restrict__ W3,
                                                 const float* __restrict__ b3,
                                                 float* __restrict__ out) {
    int t = threadIdx.x;
    size_t idx = (size_t)blockIdx.x * 256 + t;
    int row = (int)(idx >> 5);
    int c = t & 31;
    float v = Zin[idx];
#pragma unroll
    for (int s = 0; s < SK; ++s) v += P[(size_t)s * (N * HID) + idx];
    float h = fmaxf(dinv[row] * v, 0.f);
    float hw = h * W3[c];
#pragma unroll
    for (int off = 16; off > 0; off >>= 1) hw += __shfl_xor(hw, off, 32);
    if (c == 0) out[row] = hw + b3[0];
}

extern "C" void kernel_launch(void* const* d_in, const int* in_sizes, int n_in,
                              void* d_out, int out_size, void* d_ws, size_t ws_size,
                              hipStream_t stream) {
    const float* x   = (const float*)d_in[0];
    const float* adj = (const float*)d_in[1];
    const float* W1  = (const float*)d_in[2];
    const float* b1  = (const float*)d_in[3];
    const float* W2  = (const float*)d_in[4];
    const float* b2  = (const float*)d_in[5];
    const float* W3  = (const float*)d_in[6];
    const float* b3  = (const float*)d_in[7];
    float* out = (float*)d_out;

    float* dinv = (float*)d_ws;               // N floats
    float* Zs1  = dinv + N;                   // N*32 floats (1 MB)
    float* Zs2  = Zs1 + (size_t)N * HID;      // N*32 floats (1 MB)
    float* P    = Zs2 + (size_t)N * HID;      // SK*N*32 floats (32 MB)

    k_degree<<<N, 256, 0, stream>>>(adj, dinv);
    k_z1<<<N / 8, 256, 0, stream>>>(x, W1, b1, dinv, Zs1);

    k_spmm<<<dim3(N / RB, SK), 256, 0, stream>>>(adj, Zs1, P);
    k_fin_z2<<<N / 8, 256, 0, stream>>>(P, Zs1, dinv, W2, b2, Zs2);

    k_spmm<<<dim3(N / RB, SK), 256, 0, stream>>>(adj, Zs2, P);
    k_fin_out<<<N * HID / 256, 256, 0, stream>>>(P, Zs2, dinv, W3, b3, out);
}

// Round 5
// 527.447 us; speedup vs baseline: 1.4381x; 1.2201x over previous
//
#include <hip/hip_runtime.h>
#include <math.h>

#define N 8192
#define IN_DIM 128
#define HID 32

#define RB 128          // rows per spmm block
#define KT 64           // k-tile
#define SK 16           // split-K factor
#define KCHUNK (N / SK) // 512

__device__ __forceinline__ void fma4(float4& acc, float a, const float4& b) {
    acc.x = fmaf(a, b.x, acc.x);
    acc.y = fmaf(a, b.y, acc.y);
    acc.z = fmaf(a, b.z, acc.z);
    acc.w = fmaf(a, b.w, acc.w);
}

// Fused: degree + z1.  Block owns 8 rows.
//   dinv[i] = 1/sqrt(max(1 + sum_j adj[i][j], 1))   (32 lanes per row, shfl reduce)
//   Zs[i][c] = dinv[i] * (x[i] @ W1 + b1)[c]
__global__ __launch_bounds__(256) void k_deg_z1(const float* __restrict__ adj,
                                                const float* __restrict__ x,
                                                const float* __restrict__ W1,
                                                const float* __restrict__ b1,
                                                float* __restrict__ dinv,
                                                float* __restrict__ Zs) {
    __shared__ float Ws[IN_DIM * HID];  // 4096 floats
    __shared__ float xs[8 * IN_DIM];    // 1024 floats
    int t = threadIdx.x;
    int row0 = blockIdx.x * 8;
    int g = t >> 5, c = t & 31;
#pragma unroll
    for (int i = 0; i < 4; ++i)
        *(float4*)&Ws[(i * 256 + t) * 4] = *(const float4*)&W1[(i * 256 + t) * 4];
    *(float4*)&xs[t * 4] = *(const float4*)&x[(size_t)row0 * IN_DIM + t * 4];

    // degree for row (row0+g): 32 lanes, coalesced 512B segments per step
    int row = row0 + g;
    const float4* rp = (const float4*)(adj + (size_t)row * N);
    float s = 0.f;
#pragma unroll 8
    for (int i = 0; i < 64; ++i) {
        float4 v = rp[c + i * 32];
        s += v.x + v.y + v.z + v.w;
    }
#pragma unroll
    for (int off = 16; off > 0; off >>= 1) s += __shfl_xor(s, off, 64);
    float deg = fmaxf(s + 1.0f, 1.0f);  // +1 self loop
    float di = 1.0f / sqrtf(deg);
    if (c == 0) dinv[row] = di;

    __syncthreads();
    float acc = b1[c];
#pragma unroll 8
    for (int k = 0; k < IN_DIM; ++k) acc = fmaf(xs[g * IN_DIM + k], Ws[k * HID + c], acc);
    Zs[(size_t)row * HID + c] = di * acc;
}

// P[sk] = adj[rows, kchunk_sk] @ Zs[kchunk_sk, 32]   (plain stores, no atomics)
// PROVEN round-2 kernel (measured ~55us/dispatch) — unchanged.
__global__ __launch_bounds__(256) void k_spmm(const float* __restrict__ adj,
                                              const float* __restrict__ Zs,
                                              float* __restrict__ P) {
    __shared__ float As[RB][KT + 4];  // pad 4: keeps 16B alignment, spreads banks
    __shared__ float Bs[KT][HID];
    int t = threadIdx.x;
    int r0 = blockIdx.x * RB;
    int k0 = blockIdx.y * KCHUNK;
    int cg = t & 3;           // 4 col groups of 8
    int rp2 = (t >> 2) * 2;   // row pair base 0..126
    float4 acc00 = {0, 0, 0, 0}, acc01 = {0, 0, 0, 0};
    float4 acc10 = {0, 0, 0, 0}, acc11 = {0, 0, 0, 0};

    for (int kt = k0; kt < k0 + KCHUNK; kt += KT) {
        // stage A tile: 128 rows x 64 k, 8 float4 per thread, coalesced rows
#pragma unroll
        for (int i = 0; i < 8; ++i) {
            int f = i * 256 + t;         // float4 index in tile
            int row = f >> 4;            // 16 float4 per row
            int kc = (f & 15) << 2;
            *(float4*)&As[row][kc] = *(const float4*)&adj[(size_t)(r0 + row) * N + kt + kc];
        }
        // stage B tile: 64 x 32 floats, fully contiguous in global
#pragma unroll
        for (int i = 0; i < 2; ++i) {
            int f = i * 256 + t;
            ((float4*)&Bs[0][0])[f] = ((const float4*)(Zs + (size_t)kt * HID))[f];
        }
        __syncthreads();
#pragma unroll
        for (int kk = 0; kk < KT; kk += 4) {
            float a0[4], a1[4];
            *(float4*)a0 = *(const float4*)&As[rp2][kk];
            *(float4*)a1 = *(const float4*)&As[rp2 + 1][kk];
#pragma unroll
            for (int j = 0; j < 4; ++j) {
                float4 z0 = *(const float4*)&Bs[kk + j][cg * 8];
                float4 z1 = *(const float4*)&Bs[kk + j][cg * 8 + 4];
                fma4(acc00, a0[j], z0);
                fma4(acc01, a0[j], z1);
                fma4(acc10, a1[j], z0);
                fma4(acc11, a1[j], z1);
            }
        }
        __syncthreads();
    }

    float* p0 = P + (size_t)blockIdx.y * (N * HID) + (size_t)(r0 + rp2) * HID + cg * 8;
    float* p1 = p0 + HID;
    *(float4*)(p0)     = acc00;
    *(float4*)(p0 + 4) = acc01;
    *(float4*)(p1)     = acc10;
    *(float4*)(p1 + 4) = acc11;
}

// H = relu(dinv * (sum_sk P[sk] + Zs)); then Zout = dinv * (H @ W2 + b2)   (fused fin+z2)
__global__ __launch_bounds__(256) void k_fin_z2(const float* __restrict__ P,
                                                const float* __restrict__ Zin,
                                                const float* __restrict__ dinv,
                                                const float* __restrict__ W2,
                                                const float* __restrict__ b2,
                                                float* __restrict__ Zout) {
    __shared__ float Ws[HID * HID];  // 1024 floats
    __shared__ float hs[8][HID];
    int t = threadIdx.x;
    int row0 = blockIdx.x * 8;
    *(float4*)&Ws[t * 4] = *(const float4*)&W2[t * 4];
    int r = t >> 5, c = t & 31;
    size_t idx = (size_t)row0 * HID + t;   // 256 consecutive elements
    float v = Zin[idx];
#pragma unroll
    for (int s = 0; s < SK; ++s) v += P[(size_t)s * (N * HID) + idx];
    int row = row0 + r;
    hs[r][c] = fmaxf(dinv[row] * v, 0.f);
    __syncthreads();
    float acc = b2[c];
#pragma unroll
    for (int k = 0; k < HID; ++k) acc = fmaf(hs[r][k], Ws[k * HID + c], acc);
    Zout[idx] = dinv[row] * acc;
}

// H = relu(dinv * (sum_sk P[sk] + Zs)); out[i] = H[i] @ W3 + b3   (fused fin+out)
__global__ __launch_bounds__(256) void k_fin_out(const float* __restrict__ P,
                                                 const float* __restrict__ Zin,
                                                 const float* __restrict__ dinv,
                                                 const float* __restrict__ W3,
                                                 const float* __restrict__ b3,
                                                 float* __restrict__ out) {
    int t = threadIdx.x;
    size_t idx = (size_t)blockIdx.x * 256 + t;
    int row = (int)(idx >> 5);
    int c = t & 31;
    float v = Zin[idx];
#pragma unroll
    for (int s = 0; s < SK; ++s) v += P[(size_t)s * (N * HID) + idx];
    float h = fmaxf(dinv[row] * v, 0.f);
    float hw = h * W3[c];
#pragma unroll
    for (int off = 16; off > 0; off >>= 1) hw += __shfl_xor(hw, off, 32);
    if (c == 0) out[row] = hw + b3[0];
}

extern "C" void kernel_launch(void* const* d_in, const int* in_sizes, int n_in,
                              void* d_out, int out_size, void* d_ws, size_t ws_size,
                              hipStream_t stream) {
    const float* x   = (const float*)d_in[0];
    const float* adj = (const float*)d_in[1];
    const float* W1  = (const float*)d_in[2];
    const float* b1  = (const float*)d_in[3];
    const float* W2  = (const float*)d_in[4];
    const float* b2  = (const float*)d_in[5];
    const float* W3  = (const float*)d_in[6];
    const float* b3  = (const float*)d_in[7];
    float* out = (float*)d_out;

    float* dinv = (float*)d_ws;               // N floats
    float* Zs1  = dinv + N;                   // N*32 floats (1 MB)
    float* Zs2  = Zs1 + (size_t)N * HID;      // N*32 floats (1 MB)
    float* P    = Zs2 + (size_t)N * HID;      // SK*N*32 floats (16 MB)

    k_deg_z1<<<N / 8, 256, 0, stream>>>(adj, x, W1, b1, dinv, Zs1);

    k_spmm<<<dim3(N / RB, SK), 256, 0, stream>>>(adj, Zs1, P);
    k_fin_z2<<<N / 8, 256, 0, stream>>>(P, Zs1, dinv, W2, b2, Zs2);

    k_spmm<<<dim3(N / RB, SK), 256, 0, stream>>>(adj, Zs2, P);
    k_fin_out<<<N * HID / 256, 256, 0, stream>>>(P, Zs2, dinv, W3, b3, out);
}